// Round 1
// 130.075 us; speedup vs baseline: 1.0632x; 1.0632x over previous
//
#include <hip/hip_runtime.h>

// Problem constants: B=1, T=5, C=64, H=W=32, F=10
#define N_TOK   5120      // T*H*W
#define C_IN    64
#define F_OUT   10
#define FP      12        // padded row stride: [0..9]=data, [10..11]=unused pad

#define DTILE   40        // denom: Q rows staged per LDS tile
#define MTILE   40        // main: K/V rows staged per LDS tile
#define NCHUNKS 128       // denom n-chunks  -> grid 5*128 = 640 blocks
#define MCHUNKS 128       // main  m-chunks  -> grid 4*128 = 512 blocks

// ---------------------------------------------------------------------------
// Kernel A: q/k/v pointwise conv. Thread = one (n, f, arr) output value.
// 600 blocks: arr(3) x f(10) x nblk(20). 64 coalesced loads + 64 FMA each.
// Prologue: blocks [0,200) zero out (51200 f), blocks [200,220) zero dsum.
// ---------------------------------------------------------------------------
__global__ __launch_bounds__(256) void qkv_kernel(
    const float* __restrict__ x1, const float* __restrict__ x2,
    const float* __restrict__ w1, const float* __restrict__ b1,
    const float* __restrict__ w2, const float* __restrict__ b2,
    const float* __restrict__ w3, const float* __restrict__ b3,
    float* __restrict__ Q, float* __restrict__ K, float* __restrict__ V,
    float* __restrict__ out, float* __restrict__ dsum)
{
    // zero the atomic destinations for this iteration (workspace/out are
    // re-poisoned by the harness between iterations)
    if (blockIdx.x < 200)
        out[blockIdx.x * 256 + threadIdx.x] = 0.f;
    else if (blockIdx.x < 220)
        dsum[(blockIdx.x - 200) * 256 + threadIdx.x] = 0.f;

    int arr = blockIdx.x / 200;            // 0=Q, 1=K, 2=V
    int rem = blockIdx.x - arr * 200;
    int f   = rem / 20;
    int nbk = rem - f * 20;
    int n   = nbk * 256 + threadIdx.x;
    int t = n >> 10, p = n & 1023;

    const float* x    = (arr == 1) ? x2 : x1;
    const float* w    = (arr == 0) ? w1 : (arr == 1) ? w2 : w3;
    const float* bias = (arr == 0) ? b1 : (arr == 1) ? b2 : b3;
    float*       dst  = (arr == 0) ? Q  : (arr == 1) ? K  : V;

    const float* xp = x + t * (C_IN * 1024) + p;
    const float* wr = w + f * C_IN;

    float4 wv[16];
#pragma unroll
    for (int i = 0; i < 16; ++i) wv[i] = ((const float4*)wr)[i];

    float acc = 0.f;
#pragma unroll
    for (int i = 0; i < 16; ++i) {
        acc = fmaf(wv[i].x, xp[(4 * i + 0) * 1024], acc);
        acc = fmaf(wv[i].y, xp[(4 * i + 1) * 1024], acc);
        acc = fmaf(wv[i].z, xp[(4 * i + 2) * 1024], acc);
        acc = fmaf(wv[i].w, xp[(4 * i + 3) * 1024], acc);
    }
    dst[n * FP + f] = acc + bias[f];
}

// ---------------------------------------------------------------------------
// Kernel B: softmax denominators via device-scope atomics. Thread owns FOUR
// m-columns (K in regs; 3 broadcast LDS reads per j serve 104 VALU cyc).
// Grid = 5 x NCHUNKS. Epilogue: 4 atomicAdds/thread into dsum[m]
// (lane-contiguous -> store-like; 128-way per-cell contention is trivial).
// ---------------------------------------------------------------------------
__global__ __launch_bounds__(256) void denom_kernel(
    const float* __restrict__ Q, const float* __restrict__ K,
    float* __restrict__ dsum, int nclen)
{
    int mTile = blockIdx.x % 5;
    int nc    = blockIdx.x / 5;
    int tid   = threadIdx.x;
    int m0 = mTile * 1024 + tid;

    float kk[4][10];
#pragma unroll
    for (int c = 0; c < 4; ++c) {
        const float* kp = K + (m0 + c * 256) * FP;
        float4 a = ((const float4*)kp)[0];
        float4 b = ((const float4*)kp)[1];
        float2 e = ((const float2*)kp)[4];
        kk[c][0]=a.x; kk[c][1]=a.y; kk[c][2]=a.z; kk[c][3]=a.w;
        kk[c][4]=b.x; kk[c][5]=b.y; kk[c][6]=b.z; kk[c][7]=b.w;
        kk[c][8]=e.x; kk[c][9]=e.y;
    }

    __shared__ __align__(16) float sq[DTILE * FP];   // 480 floats

    float d[4] = {0.f, 0.f, 0.f, 0.f};
    int n0 = nc * nclen;
    for (int base = n0; base < n0 + nclen; base += DTILE) {
        __syncthreads();
        if (tid < DTILE * FP / 4)   // 120 coalesced float4 loads
            ((float4*)sq)[tid] = ((const float4*)(Q + base * FP))[tid];
        __syncthreads();
#pragma unroll 2
        for (int j = 0; j < DTILE; ++j) {
            const float4* qp = (const float4*)(sq + j * FP);
            float4 qa = qp[0], qb = qp[1], qc = qp[2];
            float qq[10] = {qa.x, qa.y, qa.z, qa.w, qb.x, qb.y, qb.z, qb.w,
                            qc.x, qc.y};
#pragma unroll
            for (int c = 0; c < 4; ++c) {
                float s = 0.f;
#pragma unroll
                for (int f = 0; f < F_OUT; ++f) s = fmaf(qq[f], kk[c][f], s);
                d[c] += __expf(fminf(s, 60.f));
            }
        }
    }
#pragma unroll
    for (int c = 0; c < 4; ++c) atomicAdd(&dsum[m0 + c * 256], d[c]);
}

// ---------------------------------------------------------------------------
// Kernel D: main fused pass. Thread owns FIVE rows n; K/V staged through LDS.
// invw[m] = aw0/dsum[m] computed during staging into siw[] (40 divides/block).
// coef(n,m) = w0*relu(s) + w1*sigmoid(s) + exp(s)*invw[m]
// Epilogue: 50 atomicAdds/thread directly into transposed out (zeroed by A)
// -> eliminates the 26 MB opart write + 26 MB read + reduce kernel.
// ---------------------------------------------------------------------------
__global__ __launch_bounds__(256) void main_kernel(
    const float* __restrict__ Q, const float* __restrict__ K,
    const float* __restrict__ V, const float* __restrict__ dsum,
    const float* __restrict__ aw, float* __restrict__ out, int mclen)
{
    int nTile = blockIdx.x % 4;
    int mc    = blockIdx.x / 4;
    int tid   = threadIdx.x;
    int nb = nTile * 1280 + tid;
    float w0 = aw[0], w1v = aw[1];

    float q[5][10];
#pragma unroll
    for (int r = 0; r < 5; ++r) {
        const float* qp = Q + (nb + r * 256) * FP;
        float4 a = ((const float4*)qp)[0];
        float4 b = ((const float4*)qp)[1];
        float2 e = ((const float2*)qp)[4];
        q[r][0]=a.x; q[r][1]=a.y; q[r][2]=a.z; q[r][3]=a.w;
        q[r][4]=b.x; q[r][5]=b.y; q[r][6]=b.z; q[r][7]=b.w;
        q[r][8]=e.x; q[r][9]=e.y;
    }

    float acc[5][F_OUT];
#pragma unroll
    for (int r = 0; r < 5; ++r)
#pragma unroll
        for (int f = 0; f < F_OUT; ++f) acc[r][f] = 0.f;

    __shared__ __align__(16) float sk[MTILE * FP];   // 480 floats
    __shared__ __align__(16) float sv[MTILE * FP];   // 480 floats
    __shared__ float siw[MTILE];                     // invw per staged row

    int mstart = mc * mclen;
    for (int mbase = mstart; mbase < mstart + mclen; mbase += MTILE) {
        __syncthreads();
        if (tid < 120)
            ((float4*)sk)[tid] = ((const float4*)(K + mbase * FP))[tid];
        else if (tid < 240)
            ((float4*)sv)[tid - 120] = ((const float4*)(V + mbase * FP))[tid - 120];
        if (tid < MTILE)
            siw[tid] = w0 / dsum[mbase + tid];
        __syncthreads();

#pragma unroll 2
        for (int j = 0; j < MTILE; ++j) {
            const float4* kp = (const float4*)(sk + j * FP);
            float4 ka = kp[0], kb = kp[1], kc = kp[2];
            float kk[10] = {ka.x, ka.y, ka.z, ka.w, kb.x, kb.y, kb.z, kb.w,
                            kc.x, kc.y};
            float iw = siw[j];
            const float4* vp = (const float4*)(sv + j * FP);
            float4 va = vp[0], vb = vp[1], vc = vp[2];
            float vv[10] = {va.x, va.y, va.z, va.w, vb.x, vb.y, vb.z, vb.w,
                            vc.x, vc.y};

#pragma unroll
            for (int r = 0; r < 5; ++r) {
                float s = 0.f;
#pragma unroll
                for (int f = 0; f < F_OUT; ++f) s = fmaf(q[r][f], kk[f], s);
                float rl = fmaxf(s, 0.f);
                float e  = __expf(fminf(s, 60.f));
                float sg = e * __builtin_amdgcn_rcpf(1.f + e);
                float cf = fmaf(e, iw, fmaf(w1v, sg, w0 * rl));
#pragma unroll
                for (int f = 0; f < F_OUT; ++f) acc[r][f] = fmaf(cf, vv[f], acc[r][f]);
            }
        }
    }

    // direct transposed accumulation into out[((t*10+f)<<10) + p]
#pragma unroll
    for (int r = 0; r < 5; ++r) {
        int n = nb + r * 256;
        int t = n >> 10, p = n & 1023;
        float* obase = out + ((t * F_OUT) << 10) + p;
#pragma unroll
        for (int f = 0; f < F_OUT; ++f)
            atomicAdd(obase + (f << 10), acc[r][f]);
    }
}

// ---------------------------------------------------------------------------
extern "C" void kernel_launch(void* const* d_in, const int* in_sizes, int n_in,
                              void* d_out, int out_size, void* d_ws, size_t ws_size,
                              hipStream_t stream)
{
    const float* in1 = (const float*)d_in[0];
    const float* in2 = (const float*)d_in[1];
    const float* aw  = (const float*)d_in[2];
    const float* w1  = (const float*)d_in[3];
    const float* b1  = (const float*)d_in[4];
    const float* w2  = (const float*)d_in[5];
    const float* b2  = (const float*)d_in[6];
    const float* w3  = (const float*)d_in[7];
    const float* b3  = (const float*)d_in[8];
    float* out = (float*)d_out;

    // workspace: Q/K/V padded rows + dsum. ~758 KB total.
    float* ws   = (float*)d_ws;
    float* Q    = ws;                        // N*FP
    float* K    = Q + N_TOK * FP;
    float* V    = K + N_TOK * FP;
    float* dsum = V + N_TOK * FP;            // N

    int nclen = N_TOK / NCHUNKS;   // 40 (== DTILE: single tile iter per block)
    int mclen = N_TOK / MCHUNKS;   // 40 (== MTILE)

    qkv_kernel<<<600, 256, 0, stream>>>(in1, in2, w1, b1, w2, b2, w3, b3,
                                        Q, K, V, out, dsum);
    denom_kernel<<<5 * NCHUNKS, 256, 0, stream>>>(Q, K, dsum, nclen);
    main_kernel<<<4 * MCHUNKS, 256, 0, stream>>>(Q, K, V, dsum, aw, out, mclen);
}

// Round 2
// 119.906 us; speedup vs baseline: 1.1533x; 1.0848x over previous
//
#include <hip/hip_runtime.h>

// Problem constants: B=1, T=5, C=64, H=W=32, F=10
#define N_TOK   5120      // T*H*W
#define C_IN    64
#define F_OUT   10
#define FP      12        // padded row stride: [0..9]=data, [10..11]=unused pad

#define DTILE   40        // denom: Q rows staged per LDS tile
#define MTILE   40        // main: K/V rows staged per LDS tile
#define NCHUNKS 128       // denom n-chunks  -> grid 10*128 = 1280 blocks
#define MCHUNKS 128       // main  m-chunks  -> grid 10*128 = 1280 blocks

// ---------------------------------------------------------------------------
// Kernel A: q/k/v pointwise conv. Thread = one (n, f, arr) output value.
// 600 blocks: arr(3) x f(10) x nblk(20). 64 coalesced loads + 64 FMA each.
// Prologue: blocks [0,200) zero out (51200 f), blocks [200,220) zero dsum.
// ---------------------------------------------------------------------------
__global__ __launch_bounds__(256) void qkv_kernel(
    const float* __restrict__ x1, const float* __restrict__ x2,
    const float* __restrict__ w1, const float* __restrict__ b1,
    const float* __restrict__ w2, const float* __restrict__ b2,
    const float* __restrict__ w3, const float* __restrict__ b3,
    float* __restrict__ Q, float* __restrict__ K, float* __restrict__ V,
    float* __restrict__ out, float* __restrict__ dsum)
{
    // zero the atomic destinations for this iteration (workspace/out are
    // re-poisoned by the harness between iterations)
    if (blockIdx.x < 200)
        out[blockIdx.x * 256 + threadIdx.x] = 0.f;
    else if (blockIdx.x < 220)
        dsum[(blockIdx.x - 200) * 256 + threadIdx.x] = 0.f;

    int arr = blockIdx.x / 200;            // 0=Q, 1=K, 2=V
    int rem = blockIdx.x - arr * 200;
    int f   = rem / 20;
    int nbk = rem - f * 20;
    int n   = nbk * 256 + threadIdx.x;
    int t = n >> 10, p = n & 1023;

    const float* x    = (arr == 1) ? x2 : x1;
    const float* w    = (arr == 0) ? w1 : (arr == 1) ? w2 : w3;
    const float* bias = (arr == 0) ? b1 : (arr == 1) ? b2 : b3;
    float*       dst  = (arr == 0) ? Q  : (arr == 1) ? K  : V;

    const float* xp = x + t * (C_IN * 1024) + p;
    const float* wr = w + f * C_IN;

    float4 wv[16];
#pragma unroll
    for (int i = 0; i < 16; ++i) wv[i] = ((const float4*)wr)[i];

    float acc = 0.f;
#pragma unroll
    for (int i = 0; i < 16; ++i) {
        acc = fmaf(wv[i].x, xp[(4 * i + 0) * 1024], acc);
        acc = fmaf(wv[i].y, xp[(4 * i + 1) * 1024], acc);
        acc = fmaf(wv[i].z, xp[(4 * i + 2) * 1024], acc);
        acc = fmaf(wv[i].w, xp[(4 * i + 3) * 1024], acc);
    }
    dst[n * FP + f] = acc + bias[f];
}

// ---------------------------------------------------------------------------
// Kernel B: softmax denominators via device-scope atomics. Thread owns TWO
// m-columns (K in regs). Grid = 10 mTiles x NCHUNKS = 1280 blocks
// (5 waves/SIMD for latency hiding). dsum atomic count is independent of
// the m-split: N_TOK * NCHUNKS = 655K lane-atomics total.
// ---------------------------------------------------------------------------
__global__ __launch_bounds__(256) void denom_kernel(
    const float* __restrict__ Q, const float* __restrict__ K,
    float* __restrict__ dsum, int nclen)
{
    int mTile = blockIdx.x % 10;
    int nc    = blockIdx.x / 10;
    int tid   = threadIdx.x;
    int m0 = mTile * 512 + tid;            // owns m0, m0+256

    float kk[2][10];
#pragma unroll
    for (int c = 0; c < 2; ++c) {
        const float* kp = K + (m0 + c * 256) * FP;
        float4 a = ((const float4*)kp)[0];
        float4 b = ((const float4*)kp)[1];
        float2 e = ((const float2*)kp)[4];
        kk[c][0]=a.x; kk[c][1]=a.y; kk[c][2]=a.z; kk[c][3]=a.w;
        kk[c][4]=b.x; kk[c][5]=b.y; kk[c][6]=b.z; kk[c][7]=b.w;
        kk[c][8]=e.x; kk[c][9]=e.y;
    }

    __shared__ __align__(16) float sq[DTILE * FP];   // 480 floats

    float d[2] = {0.f, 0.f};
    int n0 = nc * nclen;
    for (int base = n0; base < n0 + nclen; base += DTILE) {
        __syncthreads();
        if (tid < DTILE * FP / 4)   // 120 coalesced float4 loads
            ((float4*)sq)[tid] = ((const float4*)(Q + base * FP))[tid];
        __syncthreads();
#pragma unroll 4
        for (int j = 0; j < DTILE; ++j) {
            const float4* qp = (const float4*)(sq + j * FP);
            float4 qa = qp[0], qb = qp[1], qc = qp[2];
            float qq[10] = {qa.x, qa.y, qa.z, qa.w, qb.x, qb.y, qb.z, qb.w,
                            qc.x, qc.y};
#pragma unroll
            for (int c = 0; c < 2; ++c) {
                float s0 = 0.f, s1 = 0.f;          // 2 chains: halve dep latency
#pragma unroll
                for (int f = 0; f < 5; ++f) {
                    s0 = fmaf(qq[f],     kk[c][f],     s0);
                    s1 = fmaf(qq[f + 5], kk[c][f + 5], s1);
                }
                d[c] += __expf(fminf(s0 + s1, 60.f));
            }
        }
    }
#pragma unroll
    for (int c = 0; c < 2; ++c) atomicAdd(&dsum[m0 + c * 256], d[c]);
}

// ---------------------------------------------------------------------------
// Kernel D: main fused pass. Thread owns TWO rows n; K/V staged through LDS.
// Grid = 10 nTiles x MCHUNKS = 1280 blocks (5 waves/SIMD). Output atomic
// count is independent of the n-split: N_TOK * MCHUNKS * 10 = 6.55M.
// invw[m] = aw0/dsum[m] computed during staging into siw[].
// coef(n,m) = w0*relu(s) + w1*sigmoid(s) + exp(s)*invw[m]
// ---------------------------------------------------------------------------
__global__ __launch_bounds__(256) void main_kernel(
    const float* __restrict__ Q, const float* __restrict__ K,
    const float* __restrict__ V, const float* __restrict__ dsum,
    const float* __restrict__ aw, float* __restrict__ out, int mclen)
{
    int nTile = blockIdx.x % 10;
    int mc    = blockIdx.x / 10;
    int tid   = threadIdx.x;
    int nb = nTile * 512 + tid;            // owns nb, nb+256
    float w0 = aw[0], w1v = aw[1];

    float q[2][10];
#pragma unroll
    for (int r = 0; r < 2; ++r) {
        const float* qp = Q + (nb + r * 256) * FP;
        float4 a = ((const float4*)qp)[0];
        float4 b = ((const float4*)qp)[1];
        float2 e = ((const float2*)qp)[4];
        q[r][0]=a.x; q[r][1]=a.y; q[r][2]=a.z; q[r][3]=a.w;
        q[r][4]=b.x; q[r][5]=b.y; q[r][6]=b.z; q[r][7]=b.w;
        q[r][8]=e.x; q[r][9]=e.y;
    }

    float acc[2][F_OUT];
#pragma unroll
    for (int r = 0; r < 2; ++r)
#pragma unroll
        for (int f = 0; f < F_OUT; ++f) acc[r][f] = 0.f;

    __shared__ __align__(16) float sk[MTILE * FP];   // 480 floats
    __shared__ __align__(16) float sv[MTILE * FP];   // 480 floats
    __shared__ float siw[MTILE];                     // invw per staged row

    int mstart = mc * mclen;
    for (int mbase = mstart; mbase < mstart + mclen; mbase += MTILE) {
        __syncthreads();
        if (tid < 120)
            ((float4*)sk)[tid] = ((const float4*)(K + mbase * FP))[tid];
        else if (tid < 240)
            ((float4*)sv)[tid - 120] = ((const float4*)(V + mbase * FP))[tid - 120];
        if (tid < MTILE)
            siw[tid] = w0 / dsum[mbase + tid];
        __syncthreads();

#pragma unroll 4
        for (int j = 0; j < MTILE; ++j) {
            const float4* kp = (const float4*)(sk + j * FP);
            float4 ka = kp[0], kb = kp[1], kc = kp[2];
            float kk[10] = {ka.x, ka.y, ka.z, ka.w, kb.x, kb.y, kb.z, kb.w,
                            kc.x, kc.y};
            float iw = siw[j];
            const float4* vp = (const float4*)(sv + j * FP);
            float4 va = vp[0], vb = vp[1], vc = vp[2];
            float vv[10] = {va.x, va.y, va.z, va.w, vb.x, vb.y, vb.z, vb.w,
                            vc.x, vc.y};

#pragma unroll
            for (int r = 0; r < 2; ++r) {
                float s0 = 0.f, s1 = 0.f;          // 2 chains: halve dep latency
#pragma unroll
                for (int f = 0; f < 5; ++f) {
                    s0 = fmaf(q[r][f],     kk[f],     s0);
                    s1 = fmaf(q[r][f + 5], kk[f + 5], s1);
                }
                float s  = s0 + s1;
                float rl = fmaxf(s, 0.f);
                float e  = __expf(fminf(s, 60.f));
                float sg = e * __builtin_amdgcn_rcpf(1.f + e);
                float cf = fmaf(e, iw, fmaf(w1v, sg, w0 * rl));
#pragma unroll
                for (int f = 0; f < F_OUT; ++f) acc[r][f] = fmaf(cf, vv[f], acc[r][f]);
            }
        }
    }

    // direct transposed accumulation into out[((t*10+f)<<10) + p]
#pragma unroll
    for (int r = 0; r < 2; ++r) {
        int n = nb + r * 256;
        int t = n >> 10, p = n & 1023;
        float* obase = out + ((t * F_OUT) << 10) + p;
#pragma unroll
        for (int f = 0; f < F_OUT; ++f)
            atomicAdd(obase + (f << 10), acc[r][f]);
    }
}

// ---------------------------------------------------------------------------
extern "C" void kernel_launch(void* const* d_in, const int* in_sizes, int n_in,
                              void* d_out, int out_size, void* d_ws, size_t ws_size,
                              hipStream_t stream)
{
    const float* in1 = (const float*)d_in[0];
    const float* in2 = (const float*)d_in[1];
    const float* aw  = (const float*)d_in[2];
    const float* w1  = (const float*)d_in[3];
    const float* b1  = (const float*)d_in[4];
    const float* w2  = (const float*)d_in[5];
    const float* b2  = (const float*)d_in[6];
    const float* w3  = (const float*)d_in[7];
    const float* b3  = (const float*)d_in[8];
    float* out = (float*)d_out;

    // workspace: Q/K/V padded rows + dsum. ~758 KB total (keep small:
    // harness re-poison cost scales with touched workspace).
    float* ws   = (float*)d_ws;
    float* Q    = ws;                        // N*FP
    float* K    = Q + N_TOK * FP;
    float* V    = K + N_TOK * FP;
    float* dsum = V + N_TOK * FP;            // N

    int nclen = N_TOK / NCHUNKS;   // 40 (== DTILE: single tile iter per block)
    int mclen = N_TOK / MCHUNKS;   // 40 (== MTILE)

    qkv_kernel<<<600, 256, 0, stream>>>(in1, in2, w1, b1, w2, b2, w3, b3,
                                        Q, K, V, out, dsum);
    denom_kernel<<<10 * NCHUNKS, 256, 0, stream>>>(Q, K, dsum, nclen);
    main_kernel<<<10 * MCHUNKS, 256, 0, stream>>>(Q, K, V, dsum, aw, out, mclen);
}